// Round 2
// baseline (562.052 us; speedup 1.0000x reference)
//
#include <hip/hip_runtime.h>
#include <math.h>

// Problem constants
#define B_   4
#define T_   2048
#define D_   1024
#define H_   16
#define HD_  64
#define F_   128
#define C_   64
#define NCH  32            // T_/C_
#define BT_  8192          // B_*T_
#define BTD_ 8388608       // B_*T_*D_

typedef __bf16 bf16_t;
typedef __bf16 bf16x4 __attribute__((ext_vector_type(4)));
typedef __bf16 bf16x8 __attribute__((ext_vector_type(8)));
typedef float  f32x4  __attribute__((ext_vector_type(4)));

// ---------------------------------------------------------------------------
// K0: transpose fp32 weight [K=1024][N=1024] -> bf16 [N][K]
// ---------------------------------------------------------------------------
__global__ __launch_bounds__(256) void k_transpose_w(
    const float* __restrict__ w, bf16_t* __restrict__ wT) {
  __shared__ float tile[64][65];
  const int tid = threadIdx.x;
  const int n0 = blockIdx.x * 64;
  const int k0 = blockIdx.y * 64;
#pragma unroll
  for (int g = 0; g < 4; ++g) {
    const int k = g * 16 + (tid >> 4);
    float4 v = *(const float4*)(w + (size_t)(k0 + k) * D_ + n0 + (tid & 15) * 4);
    tile[k][(tid & 15) * 4 + 0] = v.x;
    tile[k][(tid & 15) * 4 + 1] = v.y;
    tile[k][(tid & 15) * 4 + 2] = v.z;
    tile[k][(tid & 15) * 4 + 3] = v.w;
  }
  __syncthreads();
#pragma unroll
  for (int g = 0; g < 4; ++g) {
    const int n = g * 16 + (tid >> 4);
    bf16x4 o;
#pragma unroll
    for (int i = 0; i < 4; ++i) o[i] = (__bf16)tile[(tid & 15) * 4 + i][n];
    *(bf16x4*)(wT + (size_t)(n0 + n) * D_ + k0 + (tid & 15) * 4) = o;
  }
}

// ---------------------------------------------------------------------------
// K1: resid = hs + residual (fp32 -> d_out) ; x = rmsnorm(resid)*w (bf16)
// ---------------------------------------------------------------------------
__global__ __launch_bounds__(256) void k_add_rmsnorm(
    const float* __restrict__ hs, const float* __restrict__ res,
    const float* __restrict__ w, float* __restrict__ resid_out,
    bf16_t* __restrict__ x_out) {
  const int row = blockIdx.x;
  const size_t base = (size_t)row * D_;
  const int tid = threadIdx.x;
  float4 h4 = *(const float4*)(hs + base + tid * 4);
  float4 r4 = *(const float4*)(res + base + tid * 4);
  float4 s4;
  s4.x = h4.x + r4.x; s4.y = h4.y + r4.y;
  s4.z = h4.z + r4.z; s4.w = h4.w + r4.w;
  *(float4*)(resid_out + base + tid * 4) = s4;
  float ss = s4.x * s4.x + s4.y * s4.y + s4.z * s4.z + s4.w * s4.w;
#pragma unroll
  for (int off = 32; off > 0; off >>= 1) ss += __shfl_down(ss, off);
  __shared__ float red[4];
  if ((tid & 63) == 0) red[tid >> 6] = ss;
  __syncthreads();
  const float tot = red[0] + red[1] + red[2] + red[3];
  const float rstd = rsqrtf(tot * (1.0f / D_) + 1e-5f);
  float4 w4 = *(const float4*)(w + tid * 4);
  bf16x4 xo;
  xo[0] = (__bf16)(s4.x * rstd * w4.x);
  xo[1] = (__bf16)(s4.y * rstd * w4.y);
  xo[2] = (__bf16)(s4.z * rstd * w4.z);
  xo[3] = (__bf16)(s4.w * rstd * w4.w);
  *(bf16x4*)(x_out + base + tid * 4) = xo;
}

// ---------------------------------------------------------------------------
// K2: bf16 MFMA GEMM  C[8192,1024] = A[8192,1024] @ BT[1024,1024]^T
// 128x128 tile, 4 waves (2x2), 4x4 16x16x32 frags per wave, BK=32.
// blockIdx.z selects weight/output slice (fused q,k,v projections).
// ---------------------------------------------------------------------------
template <int F32OUT>
__global__ __launch_bounds__(256) void k_gemm_mfma(
    const bf16_t* __restrict__ A, const bf16_t* __restrict__ BTb,
    void* __restrict__ Cb) {
  __shared__ bf16_t As[128 * 32];
  __shared__ bf16_t Bs[128 * 32];
  const int z = blockIdx.z;
  const bf16_t* BT = BTb + (size_t)z * (D_ * D_);
  const int tid = threadIdx.x;
  const int lane = tid & 63;
  const int wave = tid >> 6;
  const int wm = (wave >> 1) * 64;
  const int wn = (wave & 1) * 64;
  const int bm = blockIdx.y * 128;
  const int bn = blockIdx.x * 128;
  // reg-staging geometry: each thread 2x16B for A, 2x16B for B
  const int lr = tid >> 2;            // 0..63
  const int lc = (tid & 3) * 8;       // 0,8,16,24
  const size_t aoff0 = (size_t)(bm + lr) * D_ + lc;
  const size_t aoff1 = (size_t)(bm + 64 + lr) * D_ + lc;
  const size_t boff0 = (size_t)(bn + lr) * D_ + lc;
  const size_t boff1 = (size_t)(bn + 64 + lr) * D_ + lc;
  const int frow = lane & 15;
  const int fks = (lane >> 4) * 8;

  f32x4 acc[4][4] = {};
  bf16x8 a0 = *(const bf16x8*)(A + aoff0);
  bf16x8 a1 = *(const bf16x8*)(A + aoff1);
  bf16x8 b0 = *(const bf16x8*)(BT + boff0);
  bf16x8 b1 = *(const bf16x8*)(BT + boff1);

  for (int k0 = 0; k0 < D_; k0 += 32) {
    __syncthreads();                      // previous iter's LDS reads done
    *(bf16x8*)(&As[lr * 32 + lc]) = a0;
    *(bf16x8*)(&As[(64 + lr) * 32 + lc]) = a1;
    *(bf16x8*)(&Bs[lr * 32 + lc]) = b0;
    *(bf16x8*)(&Bs[(64 + lr) * 32 + lc]) = b1;
    __syncthreads();
    if (k0 + 32 < D_) {                   // prefetch next tile into regs
      a0 = *(const bf16x8*)(A + aoff0 + k0 + 32);
      a1 = *(const bf16x8*)(A + aoff1 + k0 + 32);
      b0 = *(const bf16x8*)(BT + boff0 + k0 + 32);
      b1 = *(const bf16x8*)(BT + boff1 + k0 + 32);
    }
    bf16x8 af[4], bq[4];
#pragma unroll
    for (int i = 0; i < 4; ++i) {
      af[i] = *(const bf16x8*)(&As[(wm + i * 16 + frow) * 32 + fks]);
      bq[i] = *(const bf16x8*)(&Bs[(wn + i * 16 + frow) * 32 + fks]);
    }
#pragma unroll
    for (int i = 0; i < 4; ++i)
#pragma unroll
      for (int j = 0; j < 4; ++j)
        acc[i][j] = __builtin_amdgcn_mfma_f32_16x16x32_bf16(af[i], bq[j],
                                                            acc[i][j], 0, 0, 0);
  }

  // C/D layout (HW-verified): col = lane&15, row = (lane>>4)*4 + reg
  const int crow0 = bm + wm + (lane >> 4) * 4;
  const int ccol0 = bn + wn + (lane & 15);
#pragma unroll
  for (int i = 0; i < 4; ++i)
#pragma unroll
    for (int j = 0; j < 4; ++j) {
      const size_t rb = (size_t)(crow0 + i * 16) * D_ + ccol0 + j * 16;
#pragma unroll
      for (int r = 0; r < 4; ++r) {
        if (F32OUT)
          ((float*)Cb)[rb + (size_t)r * D_] = acc[i][j][r];
        else
          ((bf16_t*)Cb + (size_t)z * ((size_t)BT_ * D_))[rb + (size_t)r * D_] =
              (__bf16)acc[i][j][r];
      }
    }
}

// ---------------------------------------------------------------------------
// K3: hedgehog feature map. p:[BT,D] bf16 head-sliced -> y = W@p_seg + b,
// softmax over concat([y,-y]). is_q: write chunk-transposed [B,H,N,F,C],
// else [B,H,T,F]. One wave per (b,t,h) row; 16 rows per block.
// ---------------------------------------------------------------------------
__global__ __launch_bounds__(256) void k_hedgehog(
    const bf16_t* __restrict__ p, const float* __restrict__ w,
    const float* __restrict__ bias, bf16_t* __restrict__ out,
    int is_q, float scale) {
  __shared__ float wsm[64][65];
  __shared__ float pvs[4][64];
  const int tid = threadIdx.x;
  for (int i = tid; i < 4096; i += 256) wsm[i >> 6][i & 63] = w[i];
  __syncthreads();
  const int e = tid & 63;
  const int rg = tid >> 6;
  const float be = bias[e];
#pragma unroll
  for (int rr = 0; rr < 4; ++rr) {
    const int rowid = blockIdx.x * 16 + rr * 4 + rg;   // (b*T + t)*H + h
    const int b = rowid / (T_ * H_);
    const int th = rowid % (T_ * H_);
    const int t = th / H_;
    const int h = th % H_;
    pvs[rg][e] = (float)p[(size_t)(b * T_ + t) * D_ + h * 64 + e];
    __syncthreads();
    float y = be;
#pragma unroll
    for (int d = 0; d < 64; ++d) y += wsm[e][d] * pvs[rg][d];
    float m = fabsf(y);
#pragma unroll
    for (int off = 32; off > 0; off >>= 1) m = fmaxf(m, __shfl_xor(m, off));
    const float e1 = expf(y - m);
    const float e2 = expf(-y - m);
    float s = e1 + e2;
#pragma unroll
    for (int off = 32; off > 0; off >>= 1) s += __shfl_xor(s, off);
    const float inv = scale / s;
    if (is_q) {
      const int n = t >> 6, c = t & 63;
      size_t ob = ((size_t)(b * H_ + h) * NCH + n) * (F_ * C_);
      out[ob + (size_t)e * C_ + c] = (__bf16)(e1 * inv);
      out[ob + (size_t)(e + 64) * C_ + c] = (__bf16)(e2 * inv);
    } else {
      size_t ob = ((size_t)(b * H_ + h) * T_ + t) * F_;
      out[ob + e] = (__bf16)(e1 * inv);
      out[ob + 64 + e] = (__bf16)(e2 * inv);
    }
  }
}

// ---------------------------------------------------------------------------
// K4: per-chunk state update  kv[b,h,n,f,d] = sum_c k[c,f]*v[c,d]   (bf16 io)
// ---------------------------------------------------------------------------
__global__ __launch_bounds__(256) void k_chunk_kv(
    const bf16_t* __restrict__ kf,   // [B,H,T,F]
    const bf16_t* __restrict__ pv,   // [BT,D]
    bf16_t* __restrict__ kvout) {    // [B,H,N,F,HD]
  __shared__ float ks[64][128];
  __shared__ float vs[64][64];
  const int blk = blockIdx.x;
  const int n = blk % NCH;
  const int h = (blk / NCH) % H_;
  const int b = blk / (NCH * H_);
  const int tid = threadIdx.x;
  const bf16_t* kbase = kf + ((size_t)(b * H_ + h) * T_ + n * 64) * F_;
#pragma unroll
  for (int g = 0; g < 4; ++g) {
    int i8 = g * 256 + tid;
    int c = i8 >> 4, f8 = (i8 & 15) * 8;
    bf16x8 k8 = *(const bf16x8*)(kbase + (size_t)c * F_ + f8);
#pragma unroll
    for (int j = 0; j < 8; ++j) ks[c][f8 + j] = (float)k8[j];
  }
#pragma unroll
  for (int g = 0; g < 2; ++g) {
    int i8 = g * 256 + tid;
    int c = i8 >> 3, d8 = (i8 & 7) * 8;
    bf16x8 v8 = *(const bf16x8*)(pv + (size_t)(b * T_ + n * 64 + c) * D_ + h * 64 + d8);
#pragma unroll
    for (int j = 0; j < 8; ++j) vs[c][d8 + j] = (float)v8[j];
  }
  __syncthreads();
  const int tx = tid & 15, ty = tid >> 4;   // f = ty*8+i, d = tx*4+j
  float acc[8][4] = {};
#pragma unroll 4
  for (int c = 0; c < 64; ++c) {
    float4 k0 = *(const float4*)(&ks[c][ty * 8]);
    float4 k1 = *(const float4*)(&ks[c][ty * 8 + 4]);
    float4 vv = *(const float4*)(&vs[c][tx * 4]);
    float ka[8] = {k0.x, k0.y, k0.z, k0.w, k1.x, k1.y, k1.z, k1.w};
    float va[4] = {vv.x, vv.y, vv.z, vv.w};
#pragma unroll
    for (int i = 0; i < 8; ++i)
#pragma unroll
      for (int j = 0; j < 4; ++j) acc[i][j] += ka[i] * va[j];
  }
  bf16_t* obase = kvout + (size_t)blk * (F_ * HD_);
#pragma unroll
  for (int i = 0; i < 8; ++i) {
    bf16x4 o4;
#pragma unroll
    for (int j = 0; j < 4; ++j) o4[j] = (__bf16)acc[i][j];
    *(bf16x4*)(obase + (ty * 8 + i) * 64 + tx * 4) = o4;
  }
}

// ---------------------------------------------------------------------------
// K5: in-place exclusive prefix over chunk axis (N=32), fp32 accumulate
// ---------------------------------------------------------------------------
__global__ __launch_bounds__(256) void k_cumsum_excl(bf16_t* __restrict__ kv) {
  const int bh = blockIdx.x >> 2;
  const int part = blockIdx.x & 3;
  const int e0 = part * 2048 + threadIdx.x;
  for (int e = e0; e < part * 2048 + 2048; e += 256) {
    float run = 0.f;
    bf16_t* base = kv + (size_t)bh * NCH * 8192 + e;
#pragma unroll
    for (int n = 0; n < NCH; ++n) {
      float v = (float)base[(size_t)n * 8192];
      base[(size_t)n * 8192] = (__bf16)run;
      run += v;
    }
  }
}

// ---------------------------------------------------------------------------
// K6: per-chunk output:  o = q @ S_excl + tril(q k^T) @ v     (bf16 io)
// ---------------------------------------------------------------------------
__global__ __launch_bounds__(256) void k_attn_chunk(
    const bf16_t* __restrict__ qfT,  // [B,H,N,F,C]
    const bf16_t* __restrict__ kf,   // [B,H,T,F]
    const bf16_t* __restrict__ pv,   // [BT,D]
    const bf16_t* __restrict__ kvx,  // S_excl [B,H,N,F,HD]
    bf16_t* __restrict__ o_tmp) {    // [BT,D] laid out (B,T,H,HD)
  __shared__ float bufA[8192];
  __shared__ float bufB[8192];
  const int blk = blockIdx.x;
  const int n = blk % NCH;
  const int h = (blk / NCH) % H_;
  const int b = blk / (NCH * H_);
  const int tid = threadIdx.x;
  const int tx = tid & 15, ty = tid >> 4;   // c = ty*4+i, {d|m} = tx*4+j

  const bf16_t* qb = qfT + (size_t)blk * (F_ * C_);
  const bf16_t* sb = kvx + (size_t)blk * (F_ * HD_);
#pragma unroll
  for (int g = 0; g < 4; ++g) {
    int i8 = g * 256 + tid;
    bf16x8 q8 = *(const bf16x8*)(qb + (size_t)i8 * 8);
    bf16x8 s8 = *(const bf16x8*)(sb + (size_t)i8 * 8);
#pragma unroll
    for (int j = 0; j < 8; ++j) bufA[i8 * 8 + j] = (float)q8[j];
#pragma unroll
    for (int j = 0; j < 8; ++j) bufB[i8 * 8 + j] = (float)s8[j];
  }
  __syncthreads();

  float acc[4][4] = {};
#pragma unroll 8
  for (int kk = 0; kk < 128; ++kk) {            // inter = qc @ S_excl
    float4 a4 = *(const float4*)(&bufA[kk * 64 + ty * 4]);
    float4 b4 = *(const float4*)(&bufB[kk * 64 + tx * 4]);
    float aa[4] = {a4.x, a4.y, a4.z, a4.w};
    float bb[4] = {b4.x, b4.y, b4.z, b4.w};
#pragma unroll
    for (int i = 0; i < 4; ++i)
#pragma unroll
      for (int j = 0; j < 4; ++j) acc[i][j] += aa[i] * bb[j];
  }
  __syncthreads();

  // restage B = kcT (transposed in LDS)
  const bf16_t* kb = kf + ((size_t)(b * H_ + h) * T_ + n * 64) * F_;
#pragma unroll
  for (int g = 0; g < 4; ++g) {
    int i8 = g * 256 + tid;
    int c = i8 & 63, f8 = (i8 >> 6) * 8;
    bf16x8 k8 = *(const bf16x8*)(kb + (size_t)c * F_ + f8);
#pragma unroll
    for (int j = 0; j < 8; ++j) bufB[(f8 + j) * 64 + c] = (float)k8[j];
  }
  __syncthreads();

  float sc[4][4] = {};
#pragma unroll 8
  for (int kk = 0; kk < 128; ++kk) {            // scores = qc @ kc^T
    float4 a4 = *(const float4*)(&bufA[kk * 64 + ty * 4]);
    float4 b4 = *(const float4*)(&bufB[kk * 64 + tx * 4]);
    float aa[4] = {a4.x, a4.y, a4.z, a4.w};
    float bb[4] = {b4.x, b4.y, b4.z, b4.w};
#pragma unroll
    for (int i = 0; i < 4; ++i)
#pragma unroll
      for (int j = 0; j < 4; ++j) sc[i][j] += aa[i] * bb[j];
  }
#pragma unroll
  for (int i = 0; i < 4; ++i)
#pragma unroll
    for (int j = 0; j < 4; ++j)
      if (tx * 4 + j > ty * 4 + i) sc[i][j] = 0.f;   // causal mask
  __syncthreads();

  // stage vs into bufA[0:4096], scT (xor-swizzled) into bufA[4096:8192]
#pragma unroll
  for (int g = 0; g < 2; ++g) {
    int i8 = g * 256 + tid;
    int m = i8 >> 3, d8 = (i8 & 7) * 8;
    bf16x8 v8 = *(const bf16x8*)(pv + (size_t)(b * T_ + n * 64 + m) * D_ + h * 64 + d8);
#pragma unroll
    for (int j = 0; j < 8; ++j) bufA[m * 64 + d8 + j] = (float)v8[j];
  }
#pragma unroll
  for (int i = 0; i < 4; ++i)
#pragma unroll
    for (int j = 0; j < 4; ++j) {
      int c = ty * 4 + i, m = tx * 4 + j;
      bufA[4096 + m * 64 + (c ^ (m & 31))] = sc[i][j];
    }
  __syncthreads();

#pragma unroll 4
  for (int m = 0; m < 64; ++m) {                // intra = scores @ v
    float4 b4 = *(const float4*)(&bufA[m * 64 + tx * 4]);
    float bb[4] = {b4.x, b4.y, b4.z, b4.w};
    const int sw = m & 31;
    float aa[4];
#pragma unroll
    for (int i = 0; i < 4; ++i) aa[i] = bufA[4096 + m * 64 + ((ty * 4 + i) ^ sw)];
#pragma unroll
    for (int i = 0; i < 4; ++i)
#pragma unroll
      for (int j = 0; j < 4; ++j) acc[i][j] += aa[i] * bb[j];
  }

#pragma unroll
  for (int i = 0; i < 4; ++i) {
    int c = ty * 4 + i;
    bf16x4 o4;
#pragma unroll
    for (int j = 0; j < 4; ++j) o4[j] = (__bf16)acc[i][j];
    *(bf16x4*)(o_tmp + (size_t)(b * T_ + n * 64 + c) * D_ + h * 64 + tx * 4) = o4;
  }
}

// ---------------------------------------------------------------------------
// Workspace layout (bytes): total 136 MiB
//   [0,16M)      x bf16 [BT,D]          -> reused as o_tmp bf16
//   [16M,22M)    wqkvT bf16 [3][N][K]
//   [22M,24M)    woT bf16 [N][K]
//   [24M,56M)    qfT bf16 [B,H,N,F,C]
//   [56M,88M)    kf bf16 [B,H,T,F]
//   [88M,136M)   pq,pk,pvb bf16 [3][BT,D];  kv bf16 (32 MiB) overlays pq+pk
// ---------------------------------------------------------------------------
extern "C" void kernel_launch(void* const* d_in, const int* in_sizes, int n_in,
                              void* d_out, int out_size, void* d_ws, size_t ws_size,
                              hipStream_t stream) {
  const float* hs   = (const float*)d_in[0];
  const float* res  = (const float*)d_in[1];
  const float* nw   = (const float*)d_in[2];
  const float* w_q  = (const float*)d_in[3];
  const float* w_k  = (const float*)d_in[4];
  const float* w_v  = (const float*)d_in[5];
  const float* w_o  = (const float*)d_in[6];
  const float* hhqw = (const float*)d_in[7];
  const float* hhqb = (const float*)d_in[8];
  const float* hhkw = (const float*)d_in[9];
  const float* hhkb = (const float*)d_in[10];

  float* out       = (float*)d_out;
  float* o_final   = out;               // [B,T,D] fp32
  float* resid_out = out + BTD_;        // [B,T,D] fp32

  char* wsb = (char*)d_ws;
  bf16_t* x_bf  = (bf16_t*)(wsb);
  bf16_t* wqkvT = (bf16_t*)(wsb + (16ull << 20));
  bf16_t* woT   = (bf16_t*)(wsb + (22ull << 20));
  bf16_t* qfT   = (bf16_t*)(wsb + (24ull << 20));
  bf16_t* kf    = (bf16_t*)(wsb + (56ull << 20));
  bf16_t* pqkv  = (bf16_t*)(wsb + (88ull << 20));
  bf16_t* pq    = pqkv;
  bf16_t* pk    = pqkv + (size_t)BTD_;
  bf16_t* pvb   = pqkv + (size_t)2 * BTD_;
  bf16_t* kv    = pqkv;                 // overlays pq+pk (dead by then)
  bf16_t* o_tmp = x_bf;                 // x dead after projections

  dim3 tgrid(16, 16);
  k_transpose_w<<<tgrid, 256, 0, stream>>>(w_q, wqkvT);
  k_transpose_w<<<tgrid, 256, 0, stream>>>(w_k, wqkvT + (size_t)D_ * D_);
  k_transpose_w<<<tgrid, 256, 0, stream>>>(w_v, wqkvT + (size_t)2 * D_ * D_);
  k_transpose_w<<<tgrid, 256, 0, stream>>>(w_o, woT);

  k_add_rmsnorm<<<BT_, 256, 0, stream>>>(hs, res, nw, resid_out, x_bf);

  k_gemm_mfma<0><<<dim3(8, 64, 3), 256, 0, stream>>>(x_bf, wqkvT, (void*)pqkv);

  k_hedgehog<<<8192, 256, 0, stream>>>(pq, hhqw, hhqb, qfT, 1, 0.08838834764831845f);
  k_hedgehog<<<8192, 256, 0, stream>>>(pk, hhkw, hhkb, kf, 0, 1.0f);

  k_chunk_kv<<<2048, 256, 0, stream>>>(kf, pvb, kv);
  k_cumsum_excl<<<256, 256, 0, stream>>>(kv);
  k_attn_chunk<<<2048, 256, 0, stream>>>(qfT, kf, pvb, kv, o_tmp);

  k_gemm_mfma<1><<<dim3(8, 64, 1), 256, 0, stream>>>(o_tmp, woT, (void*)o_final);
}

// Round 3
// 374.865 us; speedup vs baseline: 1.4993x; 1.4993x over previous
//
#include <hip/hip_runtime.h>
#include <math.h>

// Problem constants
#define B_   4
#define T_   2048
#define D_   1024
#define H_   16
#define HD_  64
#define F_   128
#define C_   64
#define NCH  32            // T_/C_
#define BT_  8192          // B_*T_
#define BTD_ 8388608       // B_*T_*D_

typedef __bf16 bf16_t;
typedef __bf16 bf16x4 __attribute__((ext_vector_type(4)));
typedef __bf16 bf16x8 __attribute__((ext_vector_type(8)));
typedef float  f32x4  __attribute__((ext_vector_type(4)));

// ---------------------------------------------------------------------------
// K0: transpose fp32 weight [K=1024][N=1024] -> bf16 [N][K]
// ---------------------------------------------------------------------------
__global__ __launch_bounds__(256) void k_transpose_w(
    const float* __restrict__ w, bf16_t* __restrict__ wT) {
  __shared__ float tile[64][65];
  const int tid = threadIdx.x;
  const int n0 = blockIdx.x * 64;
  const int k0 = blockIdx.y * 64;
#pragma unroll
  for (int g = 0; g < 4; ++g) {
    const int k = g * 16 + (tid >> 4);
    float4 v = *(const float4*)(w + (size_t)(k0 + k) * D_ + n0 + (tid & 15) * 4);
    tile[k][(tid & 15) * 4 + 0] = v.x;
    tile[k][(tid & 15) * 4 + 1] = v.y;
    tile[k][(tid & 15) * 4 + 2] = v.z;
    tile[k][(tid & 15) * 4 + 3] = v.w;
  }
  __syncthreads();
#pragma unroll
  for (int g = 0; g < 4; ++g) {
    const int n = g * 16 + (tid >> 4);
    bf16x4 o;
#pragma unroll
    for (int i = 0; i < 4; ++i) o[i] = (__bf16)tile[(tid & 15) * 4 + i][n];
    *(bf16x4*)(wT + (size_t)(n0 + n) * D_ + k0 + (tid & 15) * 4) = o;
  }
}

// ---------------------------------------------------------------------------
// K1: resid = hs + residual (fp32 -> d_out) ; x = rmsnorm(resid)*w (bf16)
// ---------------------------------------------------------------------------
__global__ __launch_bounds__(256) void k_add_rmsnorm(
    const float* __restrict__ hs, const float* __restrict__ res,
    const float* __restrict__ w, float* __restrict__ resid_out,
    bf16_t* __restrict__ x_out) {
  const int row = blockIdx.x;
  const size_t base = (size_t)row * D_;
  const int tid = threadIdx.x;
  float4 h4 = *(const float4*)(hs + base + tid * 4);
  float4 r4 = *(const float4*)(res + base + tid * 4);
  float4 s4;
  s4.x = h4.x + r4.x; s4.y = h4.y + r4.y;
  s4.z = h4.z + r4.z; s4.w = h4.w + r4.w;
  *(float4*)(resid_out + base + tid * 4) = s4;
  float ss = s4.x * s4.x + s4.y * s4.y + s4.z * s4.z + s4.w * s4.w;
#pragma unroll
  for (int off = 32; off > 0; off >>= 1) ss += __shfl_down(ss, off);
  __shared__ float red[4];
  if ((tid & 63) == 0) red[tid >> 6] = ss;
  __syncthreads();
  const float tot = red[0] + red[1] + red[2] + red[3];
  const float rstd = rsqrtf(tot * (1.0f / D_) + 1e-5f);
  float4 w4 = *(const float4*)(w + tid * 4);
  bf16x4 xo;
  xo[0] = (__bf16)(s4.x * rstd * w4.x);
  xo[1] = (__bf16)(s4.y * rstd * w4.y);
  xo[2] = (__bf16)(s4.z * rstd * w4.z);
  xo[3] = (__bf16)(s4.w * rstd * w4.w);
  *(bf16x4*)(x_out + base + tid * 4) = xo;
}

// ---------------------------------------------------------------------------
// K2: bf16 MFMA GEMM  C[8192,1024] = A[8192,1024] @ BT[1024,1024]^T
// 128x128 tile, 4 waves (2x2), 4x4 16x16x32 frags per wave, BK=32.
// blockIdx.z selects weight/output slice (fused q,k,v projections).
// ---------------------------------------------------------------------------
template <int F32OUT>
__global__ __launch_bounds__(256) void k_gemm_mfma(
    const bf16_t* __restrict__ A, const bf16_t* __restrict__ BTb,
    void* __restrict__ Cb) {
  __shared__ bf16_t As[128 * 32];
  __shared__ bf16_t Bs[128 * 32];
  const int z = blockIdx.z;
  const bf16_t* BT = BTb + (size_t)z * (D_ * D_);
  const int tid = threadIdx.x;
  const int lane = tid & 63;
  const int wave = tid >> 6;
  const int wm = (wave >> 1) * 64;
  const int wn = (wave & 1) * 64;
  const int bm = blockIdx.y * 128;
  const int bn = blockIdx.x * 128;
  const int lr = tid >> 2;            // 0..63
  const int lc = (tid & 3) * 8;       // 0,8,16,24
  const size_t aoff0 = (size_t)(bm + lr) * D_ + lc;
  const size_t aoff1 = (size_t)(bm + 64 + lr) * D_ + lc;
  const size_t boff0 = (size_t)(bn + lr) * D_ + lc;
  const size_t boff1 = (size_t)(bn + 64 + lr) * D_ + lc;
  const int frow = lane & 15;
  const int fks = (lane >> 4) * 8;

  f32x4 acc[4][4] = {};
  bf16x8 a0 = *(const bf16x8*)(A + aoff0);
  bf16x8 a1 = *(const bf16x8*)(A + aoff1);
  bf16x8 b0 = *(const bf16x8*)(BT + boff0);
  bf16x8 b1 = *(const bf16x8*)(BT + boff1);

  for (int k0 = 0; k0 < D_; k0 += 32) {
    __syncthreads();
    *(bf16x8*)(&As[lr * 32 + lc]) = a0;
    *(bf16x8*)(&As[(64 + lr) * 32 + lc]) = a1;
    *(bf16x8*)(&Bs[lr * 32 + lc]) = b0;
    *(bf16x8*)(&Bs[(64 + lr) * 32 + lc]) = b1;
    __syncthreads();
    if (k0 + 32 < D_) {
      a0 = *(const bf16x8*)(A + aoff0 + k0 + 32);
      a1 = *(const bf16x8*)(A + aoff1 + k0 + 32);
      b0 = *(const bf16x8*)(BT + boff0 + k0 + 32);
      b1 = *(const bf16x8*)(BT + boff1 + k0 + 32);
    }
    bf16x8 af[4], bq[4];
#pragma unroll
    for (int i = 0; i < 4; ++i) {
      af[i] = *(const bf16x8*)(&As[(wm + i * 16 + frow) * 32 + fks]);
      bq[i] = *(const bf16x8*)(&Bs[(wn + i * 16 + frow) * 32 + fks]);
    }
#pragma unroll
    for (int i = 0; i < 4; ++i)
#pragma unroll
      for (int j = 0; j < 4; ++j)
        acc[i][j] = __builtin_amdgcn_mfma_f32_16x16x32_bf16(af[i], bq[j],
                                                            acc[i][j], 0, 0, 0);
  }

  const int crow0 = bm + wm + (lane >> 4) * 4;
  const int ccol0 = bn + wn + (lane & 15);
#pragma unroll
  for (int i = 0; i < 4; ++i)
#pragma unroll
    for (int j = 0; j < 4; ++j) {
      const size_t rb = (size_t)(crow0 + i * 16) * D_ + ccol0 + j * 16;
#pragma unroll
      for (int r = 0; r < 4; ++r) {
        if (F32OUT)
          ((float*)Cb)[rb + (size_t)r * D_] = acc[i][j][r];
        else
          ((bf16_t*)Cb + (size_t)z * ((size_t)BT_ * D_))[rb + (size_t)r * D_] =
              (__bf16)acc[i][j][r];
      }
    }
}

// ---------------------------------------------------------------------------
// K3: hedgehog via MFMA. y[t,e] = sum_d p[t, h*64+d] * W[e,d] + b[e];
// out = softmax(concat(y,-y)) * scale, layout [B,H,T,F] (coalesced).
// Block = (b,h,n-chunk of 64 t-rows); z = 0:q / 1:k. 4 waves x 16 rows.
// ---------------------------------------------------------------------------
__global__ __launch_bounds__(256) void k_hedgehog_mfma(
    const bf16_t* __restrict__ pq, const bf16_t* __restrict__ pk,
    const float* __restrict__ wq, const float* __restrict__ wk,
    const float* __restrict__ bq, const float* __restrict__ bk,
    bf16_t* __restrict__ outq, bf16_t* __restrict__ outk) {
  const int z = blockIdx.y;
  const bf16_t* p = z ? pk : pq;
  const float* w = z ? wk : wq;
  const float* bias = z ? bk : bq;
  bf16_t* out = z ? outk : outq;
  const float scale = z ? 1.0f : 0.08838834764831845f;   // F^-0.5 on q

  const int blk = blockIdx.x;
  const int n = blk % NCH;
  const int h = (blk / NCH) % H_;
  const int b = blk / (NCH * H_);
  const int tid = threadIdx.x;
  const int lane = tid & 63;
  const int wv = tid >> 6;
  const int l15 = lane & 15;
  const int lhi = lane >> 4;

  // A-frags: p rows (t = n*64 + wv*16 + l15), d-contiguous
  const int trowA = n * 64 + wv * 16 + l15;
  bf16x8 pa[2];
#pragma unroll
  for (int s = 0; s < 2; ++s)
    pa[s] = *(const bf16x8*)(p + (size_t)(b * T_ + trowA) * D_ + h * 64 +
                             s * 32 + lhi * 8);

  // B-frags: W rows e=16j+l15, d-contiguous, f32 -> bf16 on the fly
  f32x4 acc[4] = {};
#pragma unroll
  for (int j = 0; j < 4; ++j) {
#pragma unroll
    for (int s = 0; s < 2; ++s) {
      const float* wr = w + (16 * j + l15) * 64 + s * 32 + lhi * 8;
      float4 w0 = *(const float4*)(wr);
      float4 w1 = *(const float4*)(wr + 4);
      bf16x8 wb;
      wb[0] = (__bf16)w0.x; wb[1] = (__bf16)w0.y;
      wb[2] = (__bf16)w0.z; wb[3] = (__bf16)w0.w;
      wb[4] = (__bf16)w1.x; wb[5] = (__bf16)w1.y;
      wb[6] = (__bf16)w1.z; wb[7] = (__bf16)w1.w;
      acc[j] = __builtin_amdgcn_mfma_f32_16x16x32_bf16(pa[s], wb, acc[j], 0, 0, 0);
    }
  }
  float be[4];
#pragma unroll
  for (int j = 0; j < 4; ++j) be[j] = bias[16 * j + l15];

  // softmax over e in 0..127 (= concat(y,-y)); e-values live across the
  // 16-lane group (l15) x 4 j-frags; rows = lhi*4 + r. xor masks <16 stay
  // within the 16-lane group.
  const int trowC = n * 64 + wv * 16 + lhi * 4;
#pragma unroll
  for (int r = 0; r < 4; ++r) {
    float y[4];
#pragma unroll
    for (int j = 0; j < 4; ++j) y[j] = acc[j][r] + be[j];
    float m = fmaxf(fmaxf(fabsf(y[0]), fabsf(y[1])),
                    fmaxf(fabsf(y[2]), fabsf(y[3])));
#pragma unroll
    for (int o = 1; o < 16; o <<= 1) m = fmaxf(m, __shfl_xor(m, o));
    float e1[4], e2[4], s = 0.f;
#pragma unroll
    for (int j = 0; j < 4; ++j) {
      e1[j] = expf(y[j] - m);
      e2[j] = expf(-y[j] - m);
      s += e1[j] + e2[j];
    }
#pragma unroll
    for (int o = 1; o < 16; o <<= 1) s += __shfl_xor(s, o);
    const float inv = scale / s;
    bf16_t* ob = out + ((size_t)(b * H_ + h) * T_ + trowC + r) * F_;
#pragma unroll
    for (int j = 0; j < 4; ++j) {
      ob[16 * j + l15] = (__bf16)(e1[j] * inv);
      ob[64 + 16 * j + l15] = (__bf16)(e2[j] * inv);
    }
  }
}

// ---------------------------------------------------------------------------
// K4: per-chunk state (TRANSPOSED): kvT[blk][d][f] = sum_c v[c,d] * k[c,f]
// MFMA: A = vT rows (d, c-contig), B = kT rows (f, c-contig); both staged in
// LDS with XOR swizzle (row*64 + (col ^ ((row&7)<<3))) -> conflict-free b128.
// ---------------------------------------------------------------------------
__global__ __launch_bounds__(256) void k_chunk_kv(
    const bf16_t* __restrict__ kf,   // [B,H,T,F]
    const bf16_t* __restrict__ pv,   // [BT,D] (B,T,H,HD)
    bf16_t* __restrict__ kvout) {    // [B,H,N,HD,F]
  __shared__ bf16_t kt[128 * 64];
  __shared__ bf16_t vt[64 * 64];
  const int blk = blockIdx.x;
  const int n = blk % NCH;
  const int h = (blk / NCH) % H_;
  const int b = blk / (NCH * H_);
  const int tid = threadIdx.x;
  const bf16_t* kb = kf + ((size_t)(b * H_ + h) * T_ + n * 64) * F_;
#pragma unroll
  for (int g = 0; g < 4; ++g) {
    int i8 = g * 256 + tid;
    int c = i8 >> 4, f8 = (i8 & 15) * 8;
    bf16x8 v8 = *(const bf16x8*)(kb + (size_t)c * F_ + f8);
#pragma unroll
    for (int jj = 0; jj < 8; ++jj) {
      int f = f8 + jj;
      kt[f * 64 + (c ^ ((f & 7) << 3))] = v8[jj];
    }
  }
#pragma unroll
  for (int g = 0; g < 2; ++g) {
    int i8 = g * 256 + tid;
    int m = i8 >> 3, d8 = (i8 & 7) * 8;
    bf16x8 v8 = *(const bf16x8*)(pv + (size_t)(b * T_ + n * 64 + m) * D_ +
                                 h * 64 + d8);
#pragma unroll
    for (int jj = 0; jj < 8; ++jj) {
      int d = d8 + jj;
      vt[d * 64 + (m ^ ((d & 7) << 3))] = v8[jj];
    }
  }
  __syncthreads();
  const int lane = tid & 63, wv = tid >> 6;
  const int l15 = lane & 15, lhi = lane >> 4;
  const int drow = wv * 16 + l15;
  f32x4 acc[8] = {};
#pragma unroll
  for (int s = 0; s < 2; ++s) {
    const int c0 = s * 32 + lhi * 8;
    bf16x8 va = *(const bf16x8*)(vt + drow * 64 + (c0 ^ ((drow & 7) << 3)));
#pragma unroll
    for (int j = 0; j < 8; ++j) {
      const int frow = j * 16 + l15;
      bf16x8 ka = *(const bf16x8*)(kt + frow * 64 + (c0 ^ ((frow & 7) << 3)));
      acc[j] = __builtin_amdgcn_mfma_f32_16x16x32_bf16(va, ka, acc[j], 0, 0, 0);
    }
  }
  bf16_t* ob = kvout + (size_t)blk * 8192;
#pragma unroll
  for (int j = 0; j < 8; ++j)
#pragma unroll
    for (int r = 0; r < 4; ++r) {
      int d = wv * 16 + lhi * 4 + r, f = j * 16 + l15;
      ob[d * 128 + f] = (__bf16)acc[j][r];
    }
}

// ---------------------------------------------------------------------------
// K5: in-place exclusive prefix over chunk axis (N=32), fp32 accumulate
// ---------------------------------------------------------------------------
__global__ __launch_bounds__(256) void k_cumsum_excl(bf16_t* __restrict__ kv) {
  const int bh = blockIdx.x >> 2;
  const int part = blockIdx.x & 3;
  const int e0 = part * 2048 + threadIdx.x;
  for (int e = e0; e < part * 2048 + 2048; e += 256) {
    float run = 0.f;
    bf16_t* base = kv + (size_t)bh * NCH * 8192 + e;
#pragma unroll
    for (int n = 0; n < NCH; ++n) {
      float v = (float)base[(size_t)n * 8192];
      base[(size_t)n * 8192] = (__bf16)run;
      run += v;
    }
  }
}

// ---------------------------------------------------------------------------
// K6: per-chunk output: o = q @ S_excl + tril(q k^T) @ v   — full MFMA.
// scores: A=q rows, B=k rows (both direct global, k-contig).
// inter:  A=q rows, B=kvT rows (direct global).
// intra:  A=sc rows (LDS, wave-private stripe), B=vT (LDS, XOR-swizzled).
// ---------------------------------------------------------------------------
__global__ __launch_bounds__(256) void k_attn_chunk(
    const bf16_t* __restrict__ qf,   // [B,H,T,F]
    const bf16_t* __restrict__ kf,   // [B,H,T,F]
    const bf16_t* __restrict__ pv,   // [BT,D]
    const bf16_t* __restrict__ kvx,  // S_excl^T [B,H,N,HD,F]
    bf16_t* __restrict__ o_tmp) {    // [BT,D] laid out (B,T,H,HD)
  __shared__ bf16_t scs[64 * 64];
  __shared__ bf16_t vt[64 * 64];
  const int blk = blockIdx.x;
  const int n = blk % NCH;
  const int h = (blk / NCH) % H_;
  const int b = blk / (NCH * H_);
  const int tid = threadIdx.x;
  // stage vT (block-shared; covered by the one barrier below)
#pragma unroll
  for (int g = 0; g < 2; ++g) {
    int i8 = g * 256 + tid;
    int m = i8 >> 3, d8 = (i8 & 7) * 8;
    bf16x8 v8 = *(const bf16x8*)(pv + (size_t)(b * T_ + n * 64 + m) * D_ +
                                 h * 64 + d8);
#pragma unroll
    for (int jj = 0; jj < 8; ++jj) {
      int d = d8 + jj;
      vt[d * 64 + (m ^ ((d & 7) << 3))] = v8[jj];
    }
  }
  const int lane = tid & 63, wv = tid >> 6;
  const int l15 = lane & 15, lhi = lane >> 4;
  const size_t rowbase = (size_t)(b * H_ + h) * T_ + n * 64;
  const bf16_t* qb = qf + rowbase * F_;
  const bf16_t* kb = kf + rowbase * F_;

  // q A-frags (wave-private rows)
  bf16x8 qa[4];
#pragma unroll
  for (int s = 0; s < 4; ++s)
    qa[s] = *(const bf16x8*)(qb + (wv * 16 + l15) * F_ + s * 32 + lhi * 8);

  // scores = q @ k^T
  f32x4 accS[4] = {};
#pragma unroll
  for (int j = 0; j < 4; ++j)
#pragma unroll
    for (int s = 0; s < 4; ++s) {
      bf16x8 kk = *(const bf16x8*)(kb + (j * 16 + l15) * F_ + s * 32 + lhi * 8);
      accS[j] = __builtin_amdgcn_mfma_f32_16x16x32_bf16(qa[s], kk, accS[j], 0, 0, 0);
    }
  // causal mask (tril incl diag) + bf16 -> LDS (wave-private row stripe)
#pragma unroll
  for (int j = 0; j < 4; ++j)
#pragma unroll
    for (int r = 0; r < 4; ++r) {
      int c = wv * 16 + lhi * 4 + r;
      int m = j * 16 + l15;
      float v = (m <= c) ? accS[j][r] : 0.f;
      scs[c * 64 + (m ^ ((c & 7) << 3))] = (__bf16)v;
    }

  // inter = q @ S_excl  (kvT rows d, f-contig, direct global)
  f32x4 acc[4] = {};
  const bf16_t* kvb = kvx + (size_t)blk * 8192;
#pragma unroll
  for (int j = 0; j < 4; ++j)
#pragma unroll
    for (int s = 0; s < 4; ++s) {
      bf16x8 sv = *(const bf16x8*)(kvb + (j * 16 + l15) * 128 + s * 32 + lhi * 8);
      acc[j] = __builtin_amdgcn_mfma_f32_16x16x32_bf16(qa[s], sv, acc[j], 0, 0, 0);
    }

  __syncthreads();   // vt ready (scs is same-wave, ordered by lgkmcnt)

  // intra = sc @ v
  const int crow = wv * 16 + l15;
#pragma unroll
  for (int s2 = 0; s2 < 2; ++s2) {
    const int m0 = s2 * 32 + lhi * 8;
    bf16x8 sa = *(const bf16x8*)(scs + crow * 64 + (m0 ^ ((crow & 7) << 3)));
#pragma unroll
    for (int j = 0; j < 4; ++j) {
      const int dr = j * 16 + l15;
      bf16x8 vb = *(const bf16x8*)(vt + dr * 64 + (m0 ^ ((dr & 7) << 3)));
      acc[j] = __builtin_amdgcn_mfma_f32_16x16x32_bf16(sa, vb, acc[j], 0, 0, 0);
    }
  }

#pragma unroll
  for (int j = 0; j < 4; ++j)
#pragma unroll
    for (int r = 0; r < 4; ++r) {
      int c = wv * 16 + lhi * 4 + r, d = j * 16 + l15;
      o_tmp[(size_t)(b * T_ + n * 64 + c) * D_ + h * 64 + d] = (__bf16)acc[j][r];
    }
}

// ---------------------------------------------------------------------------
// Workspace layout (bytes): total 136 MiB
//   [0,16M)      x bf16 [BT,D]          -> reused as o_tmp bf16
//   [16M,22M)    wqkvT bf16 [3][N][K]
//   [22M,24M)    woT bf16 [N][K]
//   [24M,56M)    qf bf16 [B,H,T,F]
//   [56M,88M)    kf bf16 [B,H,T,F]
//   [88M,136M)   pq,pk,pvb bf16 [3][BT,D];  kvT (32 MiB) overlays pq+pk
// ---------------------------------------------------------------------------
extern "C" void kernel_launch(void* const* d_in, const int* in_sizes, int n_in,
                              void* d_out, int out_size, void* d_ws, size_t ws_size,
                              hipStream_t stream) {
  const float* hs   = (const float*)d_in[0];
  const float* res  = (const float*)d_in[1];
  const float* nw   = (const float*)d_in[2];
  const float* w_q  = (const float*)d_in[3];
  const float* w_k  = (const float*)d_in[4];
  const float* w_v  = (const float*)d_in[5];
  const float* w_o  = (const float*)d_in[6];
  const float* hhqw = (const float*)d_in[7];
  const float* hhqb = (const float*)d_in[8];
  const float* hhkw = (const float*)d_in[9];
  const float* hhkb = (const float*)d_in[10];

  float* out       = (float*)d_out;
  float* o_final   = out;               // [B,T,D] fp32
  float* resid_out = out + BTD_;        // [B,T,D] fp32

  char* wsb = (char*)d_ws;
  bf16_t* x_bf  = (bf16_t*)(wsb);
  bf16_t* wqkvT = (bf16_t*)(wsb + (16ull << 20));
  bf16_t* woT   = (bf16_t*)(wsb + (22ull << 20));
  bf16_t* qf    = (bf16_t*)(wsb + (24ull << 20));
  bf16_t* kf    = (bf16_t*)(wsb + (56ull << 20));
  bf16_t* pqkv  = (bf16_t*)(wsb + (88ull << 20));
  bf16_t* pq    = pqkv;
  bf16_t* pk    = pqkv + (size_t)BTD_;
  bf16_t* pvb   = pqkv + (size_t)2 * BTD_;
  bf16_t* kv    = pqkv;                 // overlays pq+pk (dead by then)
  bf16_t* o_tmp = x_bf;                 // x dead after projections

  dim3 tgrid(16, 16);
  k_transpose_w<<<tgrid, 256, 0, stream>>>(w_q, wqkvT);
  k_transpose_w<<<tgrid, 256, 0, stream>>>(w_k, wqkvT + (size_t)D_ * D_);
  k_transpose_w<<<tgrid, 256, 0, stream>>>(w_v, wqkvT + (size_t)2 * D_ * D_);
  k_transpose_w<<<tgrid, 256, 0, stream>>>(w_o, woT);

  k_add_rmsnorm<<<BT_, 256, 0, stream>>>(hs, res, nw, resid_out, x_bf);

  k_gemm_mfma<0><<<dim3(8, 64, 3), 256, 0, stream>>>(x_bf, wqkvT, (void*)pqkv);

  k_hedgehog_mfma<<<dim3(2048, 2), 256, 0, stream>>>(pq, pk, hhqw, hhkw,
                                                     hhqb, hhkb, qf, kf);

  k_chunk_kv<<<2048, 256, 0, stream>>>(kf, pvb, kv);
  k_cumsum_excl<<<256, 256, 0, stream>>>(kv);
  k_attn_chunk<<<2048, 256, 0, stream>>>(qf, kf, pvb, kv, o_tmp);

  k_gemm_mfma<1><<<dim3(8, 64, 1), 256, 0, stream>>>(o_tmp, woT, (void*)o_final);
}

// Round 4
// 347.431 us; speedup vs baseline: 1.6177x; 1.0790x over previous
//
#include <hip/hip_runtime.h>
#include <math.h>

// Problem constants
#define B_   4
#define T_   2048
#define D_   1024
#define H_   16
#define HD_  64
#define F_   128
#define C_   64
#define NCH  32            // T_/C_
#define BT_  8192          // B_*T_
#define BTD_ 8388608       // B_*T_*D_

typedef __bf16 bf16_t;
typedef __bf16 bf16x4 __attribute__((ext_vector_type(4)));
typedef __bf16 bf16x8 __attribute__((ext_vector_type(8)));
typedef float  f32x4  __attribute__((ext_vector_type(4)));

// async global->LDS, 16B per lane; LDS dest is wave-uniform base + lane*16
#define GLD16(gp, lp)                                                      \
  __builtin_amdgcn_global_load_lds(                                       \
      (const __attribute__((address_space(1))) unsigned int*)(const void*)(gp), \
      (__attribute__((address_space(3))) unsigned int*)(void*)(lp), 16, 0, 0)

// ---------------------------------------------------------------------------
// K0: transpose all 4 fp32 weights [K][N] -> bf16 [N][K]  (z selects matrix)
// ---------------------------------------------------------------------------
__global__ __launch_bounds__(256) void k_transpose_all(
    const float* __restrict__ w_q, const float* __restrict__ w_k,
    const float* __restrict__ w_v, const float* __restrict__ w_o,
    bf16_t* __restrict__ wqkvT, bf16_t* __restrict__ woT) {
  const int z = blockIdx.z;
  const float* w = (z == 0) ? w_q : (z == 1) ? w_k : (z == 2) ? w_v : w_o;
  bf16_t* wT = (z < 3) ? (wqkvT + (size_t)z * D_ * D_) : woT;
  __shared__ float tile[64][65];
  const int tid = threadIdx.x;
  const int n0 = blockIdx.x * 64;
  const int k0 = blockIdx.y * 64;
#pragma unroll
  for (int g = 0; g < 4; ++g) {
    const int k = g * 16 + (tid >> 4);
    float4 v = *(const float4*)(w + (size_t)(k0 + k) * D_ + n0 + (tid & 15) * 4);
    tile[k][(tid & 15) * 4 + 0] = v.x;
    tile[k][(tid & 15) * 4 + 1] = v.y;
    tile[k][(tid & 15) * 4 + 2] = v.z;
    tile[k][(tid & 15) * 4 + 3] = v.w;
  }
  __syncthreads();
#pragma unroll
  for (int g = 0; g < 4; ++g) {
    const int n = g * 16 + (tid >> 4);
    bf16x4 o;
#pragma unroll
    for (int i = 0; i < 4; ++i) o[i] = (__bf16)tile[(tid & 15) * 4 + i][n];
    *(bf16x4*)(wT + (size_t)(n0 + n) * D_ + k0 + (tid & 15) * 4) = o;
  }
}

// ---------------------------------------------------------------------------
// K1: resid = hs + residual (fp32 -> d_out) ; x = rmsnorm(resid)*w (bf16)
// ---------------------------------------------------------------------------
__global__ __launch_bounds__(256) void k_add_rmsnorm(
    const float* __restrict__ hs, const float* __restrict__ res,
    const float* __restrict__ w, float* __restrict__ resid_out,
    bf16_t* __restrict__ x_out) {
  const int row = blockIdx.x;
  const size_t base = (size_t)row * D_;
  const int tid = threadIdx.x;
  float4 h4 = *(const float4*)(hs + base + tid * 4);
  float4 r4 = *(const float4*)(res + base + tid * 4);
  float4 s4;
  s4.x = h4.x + r4.x; s4.y = h4.y + r4.y;
  s4.z = h4.z + r4.z; s4.w = h4.w + r4.w;
  *(float4*)(resid_out + base + tid * 4) = s4;
  float ss = s4.x * s4.x + s4.y * s4.y + s4.z * s4.z + s4.w * s4.w;
#pragma unroll
  for (int off = 32; off > 0; off >>= 1) ss += __shfl_down(ss, off);
  __shared__ float red[4];
  if ((tid & 63) == 0) red[tid >> 6] = ss;
  __syncthreads();
  const float tot = red[0] + red[1] + red[2] + red[3];
  const float rstd = rsqrtf(tot * (1.0f / D_) + 1e-5f);
  float4 w4 = *(const float4*)(w + tid * 4);
  bf16x4 xo;
  xo[0] = (__bf16)(s4.x * rstd * w4.x);
  xo[1] = (__bf16)(s4.y * rstd * w4.y);
  xo[2] = (__bf16)(s4.z * rstd * w4.z);
  xo[3] = (__bf16)(s4.w * rstd * w4.w);
  *(bf16x4*)(x_out + base + tid * 4) = xo;
}

// ---------------------------------------------------------------------------
// K2: bf16 MFMA GEMM  C[8192,1024] = A[8192,1024] @ BT[1024,1024]^T
// m97 structure: 128x128 tile, BK=32, global_load_lds width-16 staging,
// 2 barriers per k-step, 4 waves x 4x4 16x16x32 frags.
// XCD swizzle: gridDim.x==8 -> XCD = blockIdx.x; each XCD owns a contiguous
// 8-tile bm panel (2MB A slice L2-resident), all bn.
// ---------------------------------------------------------------------------
template <int F32OUT>
__global__ __launch_bounds__(256) void k_gemm_mfma(
    const bf16_t* __restrict__ A, const bf16_t* __restrict__ BTb,
    void* __restrict__ Cb) {
  __shared__ bf16_t As[128 * 32];
  __shared__ bf16_t Bs[128 * 32];
  const int z = blockIdx.z;
  const bf16_t* BT = BTb + (size_t)z * (D_ * D_);
  const int tid = threadIdx.x;
  const int lane = tid & 63;
  const int wave = tid >> 6;
  const int bm = (blockIdx.x * 8 + (blockIdx.y & 7)) * 128;
  const int bn = (blockIdx.y >> 3) * 128;
  const int wm = (wave >> 1) * 64;
  const int wn = (wave & 1) * 64;
  // staging geometry: wave w seg s covers LDS rows (w*2+s)*16..+16;
  // lane l -> row +(l>>2), 8-elem chunk (l&3)
  const int srow = wave * 32 + (lane >> 2);
  const int scol = (lane & 3) * 8;
  const bf16_t* ag0 = A + (size_t)(bm + srow) * D_ + scol;
  const bf16_t* ag1 = A + (size_t)(bm + srow + 16) * D_ + scol;
  const bf16_t* bg0 = BT + (size_t)(bn + srow) * D_ + scol;
  const bf16_t* bg1 = BT + (size_t)(bn + srow + 16) * D_ + scol;
  bf16_t* lA0 = As + wave * 1024;
  bf16_t* lA1 = As + wave * 1024 + 512;
  bf16_t* lB0 = Bs + wave * 1024;
  bf16_t* lB1 = Bs + wave * 1024 + 512;
  const int frow = lane & 15;
  const int fks = (lane >> 4) * 8;

  f32x4 acc[4][4] = {};
  for (int k0 = 0; k0 < D_; k0 += 32) {
    __syncthreads();                 // previous iter's LDS reads done
    GLD16(ag0 + k0, lA0);
    GLD16(ag1 + k0, lA1);
    GLD16(bg0 + k0, lB0);
    GLD16(bg1 + k0, lB1);
    __syncthreads();                 // compiler drains vmcnt(0) before barrier
    bf16x8 af[4], bq[4];
#pragma unroll
    for (int i = 0; i < 4; ++i) {
      af[i] = *(const bf16x8*)(&As[(wm + i * 16 + frow) * 32 + fks]);
      bq[i] = *(const bf16x8*)(&Bs[(wn + i * 16 + frow) * 32 + fks]);
    }
#pragma unroll
    for (int i = 0; i < 4; ++i)
#pragma unroll
      for (int j = 0; j < 4; ++j)
        acc[i][j] = __builtin_amdgcn_mfma_f32_16x16x32_bf16(af[i], bq[j],
                                                            acc[i][j], 0, 0, 0);
  }

  const int crow0 = bm + wm + (lane >> 4) * 4;
  const int ccol0 = bn + wn + (lane & 15);
#pragma unroll
  for (int i = 0; i < 4; ++i)
#pragma unroll
    for (int j = 0; j < 4; ++j) {
      const size_t rb = (size_t)(crow0 + i * 16) * D_ + ccol0 + j * 16;
#pragma unroll
      for (int r = 0; r < 4; ++r) {
        if (F32OUT)
          ((float*)Cb)[rb + (size_t)r * D_] = acc[i][j][r];
        else
          ((bf16_t*)Cb + (size_t)z * ((size_t)BT_ * D_))[rb + (size_t)r * D_] =
              (__bf16)acc[i][j][r];
      }
    }
}

// ---------------------------------------------------------------------------
// K3: hedgehog via MFMA. y[t,e] = sum_d p[t, h*64+d] * W[e,d] + b[e];
// out = softmax(concat(y,-y)) * scale, layout [B,H,T,F] (coalesced).
// ---------------------------------------------------------------------------
__global__ __launch_bounds__(256) void k_hedgehog_mfma(
    const bf16_t* __restrict__ pq, const bf16_t* __restrict__ pk,
    const float* __restrict__ wq, const float* __restrict__ wk,
    const float* __restrict__ bq, const float* __restrict__ bk,
    bf16_t* __restrict__ outq, bf16_t* __restrict__ outk) {
  const int z = blockIdx.y;
  const bf16_t* p = z ? pk : pq;
  const float* w = z ? wk : wq;
  const float* bias = z ? bk : bq;
  bf16_t* out = z ? outk : outq;
  const float scale = z ? 1.0f : 0.08838834764831845f;   // F^-0.5 on q

  const int blk = blockIdx.x;
  const int n = blk % NCH;
  const int h = (blk / NCH) % H_;
  const int b = blk / (NCH * H_);
  const int tid = threadIdx.x;
  const int lane = tid & 63;
  const int wv = tid >> 6;
  const int l15 = lane & 15;
  const int lhi = lane >> 4;

  const int trowA = n * 64 + wv * 16 + l15;
  bf16x8 pa[2];
#pragma unroll
  for (int s = 0; s < 2; ++s)
    pa[s] = *(const bf16x8*)(p + (size_t)(b * T_ + trowA) * D_ + h * 64 +
                             s * 32 + lhi * 8);

  f32x4 acc[4] = {};
#pragma unroll
  for (int j = 0; j < 4; ++j) {
#pragma unroll
    for (int s = 0; s < 2; ++s) {
      const float* wr = w + (16 * j + l15) * 64 + s * 32 + lhi * 8;
      float4 w0 = *(const float4*)(wr);
      float4 w1 = *(const float4*)(wr + 4);
      bf16x8 wb;
      wb[0] = (__bf16)w0.x; wb[1] = (__bf16)w0.y;
      wb[2] = (__bf16)w0.z; wb[3] = (__bf16)w0.w;
      wb[4] = (__bf16)w1.x; wb[5] = (__bf16)w1.y;
      wb[6] = (__bf16)w1.z; wb[7] = (__bf16)w1.w;
      acc[j] = __builtin_amdgcn_mfma_f32_16x16x32_bf16(pa[s], wb, acc[j], 0, 0, 0);
    }
  }
  float be[4];
#pragma unroll
  for (int j = 0; j < 4; ++j) be[j] = bias[16 * j + l15];

  const int trowC = n * 64 + wv * 16 + lhi * 4;
#pragma unroll
  for (int r = 0; r < 4; ++r) {
    float y[4];
#pragma unroll
    for (int j = 0; j < 4; ++j) y[j] = acc[j][r] + be[j];
    float m = fmaxf(fmaxf(fabsf(y[0]), fabsf(y[1])),
                    fmaxf(fabsf(y[2]), fabsf(y[3])));
#pragma unroll
    for (int o = 1; o < 16; o <<= 1) m = fmaxf(m, __shfl_xor(m, o));
    float e1[4], e2[4], s = 0.f;
#pragma unroll
    for (int j = 0; j < 4; ++j) {
      e1[j] = expf(y[j] - m);
      e2[j] = expf(-y[j] - m);
      s += e1[j] + e2[j];
    }
#pragma unroll
    for (int o = 1; o < 16; o <<= 1) s += __shfl_xor(s, o);
    const float inv = scale / s;
    bf16_t* ob = out + ((size_t)(b * H_ + h) * T_ + trowC + r) * F_;
#pragma unroll
    for (int j = 0; j < 4; ++j) {
      ob[16 * j + l15] = (__bf16)(e1[j] * inv);
      ob[64 + 16 * j + l15] = (__bf16)(e2[j] * inv);
    }
  }
}

// ---------------------------------------------------------------------------
// K4: per-chunk state (TRANSPOSED): kvT[blk][d][f] = sum_c v[c,d] * k[c,f]
// ---------------------------------------------------------------------------
__global__ __launch_bounds__(256) void k_chunk_kv(
    const bf16_t* __restrict__ kf,   // [B,H,T,F]
    const bf16_t* __restrict__ pv,   // [BT,D] (B,T,H,HD)
    bf16_t* __restrict__ kvout) {    // [B,H,N,HD,F]
  __shared__ bf16_t kt[128 * 64];
  __shared__ bf16_t vt[64 * 64];
  const int blk = blockIdx.x;
  const int n = blk % NCH;
  const int h = (blk / NCH) % H_;
  const int b = blk / (NCH * H_);
  const int tid = threadIdx.x;
  const bf16_t* kb = kf + ((size_t)(b * H_ + h) * T_ + n * 64) * F_;
#pragma unroll
  for (int g = 0; g < 4; ++g) {
    int i8 = g * 256 + tid;
    int c = i8 >> 4, f8 = (i8 & 15) * 8;
    bf16x8 v8 = *(const bf16x8*)(kb + (size_t)c * F_ + f8);
#pragma unroll
    for (int jj = 0; jj < 8; ++jj) {
      int f = f8 + jj;
      kt[f * 64 + (c ^ ((f & 7) << 3))] = v8[jj];
    }
  }
#pragma unroll
  for (int g = 0; g < 2; ++g) {
    int i8 = g * 256 + tid;
    int m = i8 >> 3, d8 = (i8 & 7) * 8;
    bf16x8 v8 = *(const bf16x8*)(pv + (size_t)(b * T_ + n * 64 + m) * D_ +
                                 h * 64 + d8);
#pragma unroll
    for (int jj = 0; jj < 8; ++jj) {
      int d = d8 + jj;
      vt[d * 64 + (m ^ ((d & 7) << 3))] = v8[jj];
    }
  }
  __syncthreads();
  const int lane = tid & 63, wv = tid >> 6;
  const int l15 = lane & 15, lhi = lane >> 4;
  const int drow = wv * 16 + l15;
  f32x4 acc[8] = {};
#pragma unroll
  for (int s = 0; s < 2; ++s) {
    const int c0 = s * 32 + lhi * 8;
    bf16x8 va = *(const bf16x8*)(vt + drow * 64 + (c0 ^ ((drow & 7) << 3)));
#pragma unroll
    for (int j = 0; j < 8; ++j) {
      const int frow = j * 16 + l15;
      bf16x8 ka = *(const bf16x8*)(kt + frow * 64 + (c0 ^ ((frow & 7) << 3)));
      acc[j] = __builtin_amdgcn_mfma_f32_16x16x32_bf16(va, ka, acc[j], 0, 0, 0);
    }
  }
  bf16_t* ob = kvout + (size_t)blk * 8192;
#pragma unroll
  for (int j = 0; j < 8; ++j)
#pragma unroll
    for (int r = 0; r < 4; ++r) {
      int d = wv * 16 + lhi * 4 + r, f = j * 16 + l15;
      ob[d * 128 + f] = (__bf16)acc[j][r];
    }
}

// ---------------------------------------------------------------------------
// K5: exclusive prefix over chunk axis (N=32): register-resident scan.
// Thread owns 4 contiguous elements; 32 independent loads in flight, then
// scan in regs, then 32 stores. Grid 512 = 64 bh x 8 slices.
// ---------------------------------------------------------------------------
__global__ __launch_bounds__(256) void k_cumsum_excl(bf16_t* __restrict__ kv) {
  const int bh = blockIdx.x >> 3;
  const int slice = blockIdx.x & 7;
  const int e = slice * 1024 + threadIdx.x * 4;
  bf16_t* base = kv + (size_t)bh * NCH * 8192 + e;
  bf16x4 vals[NCH];
#pragma unroll
  for (int n = 0; n < NCH; ++n) vals[n] = *(const bf16x4*)(base + (size_t)n * 8192);
  float run[4] = {0.f, 0.f, 0.f, 0.f};
#pragma unroll
  for (int n = 0; n < NCH; ++n) {
    bf16x4 o;
#pragma unroll
    for (int j = 0; j < 4; ++j) {
      o[j] = (__bf16)run[j];
      run[j] += (float)vals[n][j];
    }
    *(bf16x4*)(base + (size_t)n * 8192) = o;
  }
}

// ---------------------------------------------------------------------------
// K6: per-chunk output: o = q @ S_excl + tril(q k^T) @ v   — full MFMA.
// ---------------------------------------------------------------------------
__global__ __launch_bounds__(256) void k_attn_chunk(
    const bf16_t* __restrict__ qf,   // [B,H,T,F]
    const bf16_t* __restrict__ kf,   // [B,H,T,F]
    const bf16_t* __restrict__ pv,   // [BT,D]
    const bf16_t* __restrict__ kvx,  // S_excl^T [B,H,N,HD,F]
    bf16_t* __restrict__ o_tmp) {    // [BT,D] laid out (B,T,H,HD)
  __shared__ bf16_t scs[64 * 64];
  __shared__ bf16_t vt[64 * 64];
  const int blk = blockIdx.x;
  const int n = blk % NCH;
  const int h = (blk / NCH) % H_;
  const int b = blk / (NCH * H_);
  const int tid = threadIdx.x;
#pragma unroll
  for (int g = 0; g < 2; ++g) {
    int i8 = g * 256 + tid;
    int m = i8 >> 3, d8 = (i8 & 7) * 8;
    bf16x8 v8 = *(const bf16x8*)(pv + (size_t)(b * T_ + n * 64 + m) * D_ +
                                 h * 64 + d8);
#pragma unroll
    for (int jj = 0; jj < 8; ++jj) {
      int d = d8 + jj;
      vt[d * 64 + (m ^ ((d & 7) << 3))] = v8[jj];
    }
  }
  const int lane = tid & 63, wv = tid >> 6;
  const int l15 = lane & 15, lhi = lane >> 4;
  const size_t rowbase = (size_t)(b * H_ + h) * T_ + n * 64;
  const bf16_t* qb = qf + rowbase * F_;
  const bf16_t* kb = kf + rowbase * F_;

  bf16x8 qa[4];
#pragma unroll
  for (int s = 0; s < 4; ++s)
    qa[s] = *(const bf16x8*)(qb + (wv * 16 + l15) * F_ + s * 32 + lhi * 8);

  f32x4 accS[4] = {};
#pragma unroll
  for (int j = 0; j < 4; ++j)
#pragma unroll
    for (int s = 0; s < 4; ++s) {
      bf16x8 kk = *(const bf16x8*)(kb + (j * 16 + l15) * F_ + s * 32 + lhi * 8);
      accS[j] = __builtin_amdgcn_mfma_f32_16x16x32_bf16(qa[s], kk, accS[j], 0, 0, 0);
    }
#pragma unroll
  for (int j = 0; j < 4; ++j)
#pragma unroll
    for (int r = 0; r < 4; ++r) {
      int c = wv * 16 + lhi * 4 + r;
      int m = j * 16 + l15;
      float v = (m <= c) ? accS[j][r] : 0.f;
      scs[c * 64 + (m ^ ((c & 7) << 3))] = (__bf16)v;
    }

  f32x4 acc[4] = {};
  const bf16_t* kvb = kvx + (size_t)blk * 8192;
#pragma unroll
  for (int j = 0; j < 4; ++j)
#pragma unroll
    for (int s = 0; s < 4; ++s) {
      bf16x8 sv = *(const bf16x8*)(kvb + (j * 16 + l15) * 128 + s * 32 + lhi * 8);
      acc[j] = __builtin_amdgcn_mfma_f32_16x16x32_bf16(qa[s], sv, acc[j], 0, 0, 0);
    }

  __syncthreads();   // vt ready (scs writes are same-wave, lgkmcnt-ordered)

  const int crow = wv * 16 + l15;
#pragma unroll
  for (int s2 = 0; s2 < 2; ++s2) {
    const int m0 = s2 * 32 + lhi * 8;
    bf16x8 sa = *(const bf16x8*)(scs + crow * 64 + (m0 ^ ((crow & 7) << 3)));
#pragma unroll
    for (int j = 0; j < 4; ++j) {
      const int dr = j * 16 + l15;
      bf16x8 vb = *(const bf16x8*)(vt + dr * 64 + (m0 ^ ((dr & 7) << 3)));
      acc[j] = __builtin_amdgcn_mfma_f32_16x16x32_bf16(sa, vb, acc[j], 0, 0, 0);
    }
  }

#pragma unroll
  for (int j = 0; j < 4; ++j)
#pragma unroll
    for (int r = 0; r < 4; ++r) {
      int c = wv * 16 + lhi * 4 + r, d = j * 16 + l15;
      o_tmp[(size_t)(b * T_ + n * 64 + c) * D_ + h * 64 + d] = (__bf16)acc[j][r];
    }
}

// ---------------------------------------------------------------------------
// Workspace layout (bytes): total 136 MiB
//   [0,16M)      x bf16 [BT,D]          -> reused as o_tmp bf16
//   [16M,22M)    wqkvT bf16 [3][N][K]
//   [22M,24M)    woT bf16 [N][K]
//   [24M,56M)    qf bf16 [B,H,T,F]
//   [56M,88M)    kf bf16 [B,H,T,F]
//   [88M,136M)   pq,pk,pvb bf16 [3][BT,D];  kvT (32 MiB) overlays pq+pk
// ---------------------------------------------------------------------------
extern "C" void kernel_launch(void* const* d_in, const int* in_sizes, int n_in,
                              void* d_out, int out_size, void* d_ws, size_t ws_size,
                              hipStream_t stream) {
  const float* hs   = (const float*)d_in[0];
  const float* res  = (const float*)d_in[1];
  const float* nw   = (const float*)d_in[2];
  const float* w_q  = (const float*)d_in[3];
  const float* w_k  = (const float*)d_in[4];
  const float* w_v  = (const float*)d_in[5];
  const float* w_o  = (const float*)d_in[6];
  const float* hhqw = (const float*)d_in[7];
  const float* hhqb = (const float*)d_in[8];
  const float* hhkw = (const float*)d_in[9];
  const float* hhkb = (const float*)d_in[10];

  float* out       = (float*)d_out;
  float* o_final   = out;               // [B,T,D] fp32
  float* resid_out = out + BTD_;        // [B,T,D] fp32

  char* wsb = (char*)d_ws;
  bf16_t* x_bf  = (bf16_t*)(wsb);
  bf16_t* wqkvT = (bf16_t*)(wsb + (16ull << 20));
  bf16_t* woT   = (bf16_t*)(wsb + (22ull << 20));
  bf16_t* qf    = (bf16_t*)(wsb + (24ull << 20));
  bf16_t* kf    = (bf16_t*)(wsb + (56ull << 20));
  bf16_t* pqkv  = (bf16_t*)(wsb + (88ull << 20));
  bf16_t* pq    = pqkv;
  bf16_t* pk    = pqkv + (size_t)BTD_;
  bf16_t* pvb   = pqkv + (size_t)2 * BTD_;
  bf16_t* kv    = pqkv;                 // overlays pq+pk (dead by then)
  bf16_t* o_tmp = x_bf;                 // x dead after projections

  k_transpose_all<<<dim3(16, 16, 4), 256, 0, stream>>>(w_q, w_k, w_v, w_o,
                                                       wqkvT, woT);

  k_add_rmsnorm<<<BT_, 256, 0, stream>>>(hs, res, nw, resid_out, x_bf);

  k_gemm_mfma<0><<<dim3(8, 64, 3), 256, 0, stream>>>(x_bf, wqkvT, (void*)pqkv);

  k_hedgehog_mfma<<<dim3(2048, 2), 256, 0, stream>>>(pq, pk, hhqw, hhkw,
                                                     hhqb, hhkb, qf, kf);

  k_chunk_kv<<<2048, 256, 0, stream>>>(kf, pvb, kv);
  k_cumsum_excl<<<512, 256, 0, stream>>>(kv);
  k_attn_chunk<<<2048, 256, 0, stream>>>(qf, kf, pvb, kv, o_tmp);

  k_gemm_mfma<1><<<dim3(8, 64, 1), 256, 0, stream>>>(o_tmp, woT, (void*)o_final);
}

// Round 5
// 299.599 us; speedup vs baseline: 1.8760x; 1.1597x over previous
//
#include <hip/hip_runtime.h>
#include <math.h>

#define B_   4
#define T_   2048
#define D_   1024
#define H_   16
#define HD_  64
#define F_   128
#define C_   64
#define NCH  32
#define BT_  8192
#define BTD_ 8388608

typedef __bf16 bf16_t;
typedef __bf16 bf16x4 __attribute__((ext_vector_type(4)));
typedef __bf16 bf16x8 __attribute__((ext_vector_type(8)));
typedef float  f32x4  __attribute__((ext_vector_type(4)));

// async global->LDS, 16B/lane; LDS dest wave-uniform base + lane*16
#define GLD16(gp, lp)                                                      \
  __builtin_amdgcn_global_load_lds(                                       \
      (const __attribute__((address_space(1))) unsigned int*)(const void*)(gp), \
      (__attribute__((address_space(3))) unsigned int*)(void*)(lp), 16, 0, 0)

// ---------------------------------------------------------------------------
// K0: transpose 4 fp32 weights [K][N] -> bf16 [N][K]; z=4 converts hh weights
// ---------------------------------------------------------------------------
__global__ __launch_bounds__(256) void k_transpose_all(
    const float* __restrict__ w_q, const float* __restrict__ w_k,
    const float* __restrict__ w_v, const float* __restrict__ w_o,
    const float* __restrict__ hhqw, const float* __restrict__ hhkw,
    bf16_t* __restrict__ wqkvT, bf16_t* __restrict__ woT,
    bf16_t* __restrict__ hhbf) {
  const int z = blockIdx.z;
  const int tid = threadIdx.x;
  if (z == 4) {                       // hh weights: plain fp32->bf16 copy
    const int gid = blockIdx.y * 16 + blockIdx.x;
    if (gid < 32) {
      const int i = gid * 256 + tid;
      const float v = (i < 4096) ? hhqw[i] : hhkw[i - 4096];
      hhbf[i] = (__bf16)v;
    }
    return;
  }
  const float* w = (z == 0) ? w_q : (z == 1) ? w_k : (z == 2) ? w_v : w_o;
  bf16_t* wT = (z < 3) ? (wqkvT + (size_t)z * D_ * D_) : woT;
  __shared__ float tile[64][65];
  const int n0 = blockIdx.x * 64;
  const int k0 = blockIdx.y * 64;
#pragma unroll
  for (int g = 0; g < 4; ++g) {
    const int k = g * 16 + (tid >> 4);
    float4 v = *(const float4*)(w + (size_t)(k0 + k) * D_ + n0 + (tid & 15) * 4);
    tile[k][(tid & 15) * 4 + 0] = v.x;
    tile[k][(tid & 15) * 4 + 1] = v.y;
    tile[k][(tid & 15) * 4 + 2] = v.z;
    tile[k][(tid & 15) * 4 + 3] = v.w;
  }
  __syncthreads();
#pragma unroll
  for (int g = 0; g < 4; ++g) {
    const int n = g * 16 + (tid >> 4);
    bf16x4 o;
#pragma unroll
    for (int i = 0; i < 4; ++i) o[i] = (__bf16)tile[(tid & 15) * 4 + i][n];
    *(bf16x4*)(wT + (size_t)(n0 + n) * D_ + k0 + (tid & 15) * 4) = o;
  }
}

// ---------------------------------------------------------------------------
// K1: resid = hs + residual (fp32 -> d_out) ; x = rmsnorm(resid)*w (bf16)
// ---------------------------------------------------------------------------
__global__ __launch_bounds__(256) void k_add_rmsnorm(
    const float* __restrict__ hs, const float* __restrict__ res,
    const float* __restrict__ w, float* __restrict__ resid_out,
    bf16_t* __restrict__ x_out) {
  const int row = blockIdx.x;
  const size_t base = (size_t)row * D_;
  const int tid = threadIdx.x;
  float4 h4 = *(const float4*)(hs + base + tid * 4);
  float4 r4 = *(const float4*)(res + base + tid * 4);
  float4 s4;
  s4.x = h4.x + r4.x; s4.y = h4.y + r4.y;
  s4.z = h4.z + r4.z; s4.w = h4.w + r4.w;
  *(float4*)(resid_out + base + tid * 4) = s4;
  float ss = s4.x * s4.x + s4.y * s4.y + s4.z * s4.z + s4.w * s4.w;
#pragma unroll
  for (int off = 32; off > 0; off >>= 1) ss += __shfl_down(ss, off);
  __shared__ float red[4];
  if ((tid & 63) == 0) red[tid >> 6] = ss;
  __syncthreads();
  const float tot = red[0] + red[1] + red[2] + red[3];
  const float rstd = rsqrtf(tot * (1.0f / D_) + 1e-5f);
  float4 w4 = *(const float4*)(w + tid * 4);
  bf16x4 xo;
  xo[0] = (__bf16)(s4.x * rstd * w4.x);
  xo[1] = (__bf16)(s4.y * rstd * w4.y);
  xo[2] = (__bf16)(s4.z * rstd * w4.z);
  xo[3] = (__bf16)(s4.w * rstd * w4.w);
  *(bf16x4*)(x_out + base + tid * 4) = xo;
}

// ---------------------------------------------------------------------------
// K2: bf16 MFMA GEMM, 128x128 tile, BK=32, 2-phase dbuf + T2 swizzle.
// LDS rows = 64B = 4 chunks of 16B; swizzle chunk ^= S2(r) = (r&3)^((r>>2)&3)
// applied via pre-swizzled global source (linear GLD16 dest) + swizzled read.
// ---------------------------------------------------------------------------
template <int F32OUT>
__global__ __launch_bounds__(256) void k_gemm_mfma(
    const bf16_t* __restrict__ A, const bf16_t* __restrict__ BTb,
    void* __restrict__ Cb) {
  __shared__ bf16_t As[2][128 * 32];
  __shared__ bf16_t Bs[2][128 * 32];
  const int z = blockIdx.z;
  const bf16_t* BT = BTb + (size_t)z * (D_ * D_);
  const int tid = threadIdx.x;
  const int lane = tid & 63;
  const int wave = tid >> 6;
  const int bm = (blockIdx.x * 8 + (blockIdx.y & 7)) * 128;
  const int bn = (blockIdx.y >> 3) * 128;
  const int wm = (wave >> 1) * 64;
  const int wn = (wave & 1) * 64;
  // staging: chunk_lin = wave*128 + call*64 + lane; row = cl>>2, pc = cl&3
  const int r0 = wave * 32 + (lane >> 2);            // call0 row (call1 = +16)
  const int ssw = (((lane >> 2) & 3) ^ (lane >> 4)); // S2(r0) == S2(r0+16)
  const int scol = (((lane & 3) ^ ssw) << 3);        // pre-swizzled col (elems)
  const bf16_t* ap0 = A + (size_t)(bm + r0) * D_ + scol;
  const bf16_t* ap1 = A + (size_t)(bm + r0 + 16) * D_ + scol;
  const bf16_t* bp0 = BT + (size_t)(bn + r0) * D_ + scol;
  const bf16_t* bp1 = BT + (size_t)(bn + r0 + 16) * D_ + scol;
  const int lb0 = wave * 1024;       // LDS elem base, call0
  const int lb1 = wave * 1024 + 512; // call1
  const int frow = lane & 15;
  const int lhi = lane >> 4;
  const int rsw = ((frow & 3) ^ ((frow >> 2) & 3)); // S2(frag row)
  const int rcol = ((lhi ^ rsw) << 3);              // swizzled read col (elems)

  f32x4 acc[4][4] = {};
  // prologue: stage k=0 into buf0
  GLD16(ap0, &As[0][lb0]);
  GLD16(ap1, &As[0][lb1]);
  GLD16(bp0, &Bs[0][lb0]);
  GLD16(bp1, &Bs[0][lb1]);
  __syncthreads();

  for (int k0 = 0; k0 < D_; k0 += 32) {
    const int cur = (k0 >> 5) & 1;
    if (k0 + 32 < D_) {              // issue next tile BEFORE compute
      const int nxt = cur ^ 1;
      GLD16(ap0 + k0 + 32, &As[nxt][lb0]);
      GLD16(ap1 + k0 + 32, &As[nxt][lb1]);
      GLD16(bp0 + k0 + 32, &Bs[nxt][lb0]);
      GLD16(bp1 + k0 + 32, &Bs[nxt][lb1]);
    }
    bf16x8 af[4], bq[4];
#pragma unroll
    for (int i = 0; i < 4; ++i) {
      af[i] = *(const bf16x8*)(&As[cur][(wm + i * 16 + frow) * 32 + rcol]);
      bq[i] = *(const bf16x8*)(&Bs[cur][(wn + i * 16 + frow) * 32 + rcol]);
    }
#pragma unroll
    for (int i = 0; i < 4; ++i)
#pragma unroll
      for (int j = 0; j < 4; ++j)
        acc[i][j] = __builtin_amdgcn_mfma_f32_16x16x32_bf16(af[i], bq[j],
                                                            acc[i][j], 0, 0, 0);
    __syncthreads();                 // drains vmcnt(0): next buf ready
  }

  const int crow0 = bm + wm + (lane >> 4) * 4;
  const int ccol0 = bn + wn + (lane & 15);
#pragma unroll
  for (int i = 0; i < 4; ++i)
#pragma unroll
    for (int j = 0; j < 4; ++j) {
      const size_t rb = (size_t)(crow0 + i * 16) * D_ + ccol0 + j * 16;
#pragma unroll
      for (int r = 0; r < 4; ++r) {
        if (F32OUT)
          ((float*)Cb)[rb + (size_t)r * D_] = acc[i][j][r];
        else
          ((bf16_t*)Cb + (size_t)z * ((size_t)BT_ * D_))[rb + (size_t)r * D_] =
              (__bf16)acc[i][j][r];
      }
    }
}

// featT swizzle: rows f of 64 elems (8 chunks); S(f) = (f&7) ^ ((f>>3)&7)
// (depends on low AND mid f-bits so both frag reads (f=16j+l15) and
//  column gathers (f=fc*8+jj) spread across bank quads)
__device__ __forceinline__ int swF(int f) { return (f & 7) ^ ((f >> 3) & 7); }

// ---------------------------------------------------------------------------
// K3: hedgehog (+fused chunk_kv for z=1).
// feats -> featT LDS [f=128][c=64] (swizzled) -> coalesced global [B,H,T,F];
// z=1: kvT[d][f] = sum_c v[c,d]*feat[c,f] via MFMA from featT + vt.
// ---------------------------------------------------------------------------
__global__ __launch_bounds__(256) void k_hedgehog_kv(
    const bf16_t* __restrict__ pq, const bf16_t* __restrict__ pk,
    const bf16_t* __restrict__ hhbf,
    const float* __restrict__ bq, const float* __restrict__ bk,
    const bf16_t* __restrict__ pv,
    bf16_t* __restrict__ outq, bf16_t* __restrict__ outk,
    bf16_t* __restrict__ kvout) {
  __shared__ bf16_t featT[128 * 64];   // 16KB
  __shared__ bf16_t vt[64 * 64];       // 8KB (z=1)
  const int z = blockIdx.y;
  const bf16_t* p = z ? pk : pq;
  const bf16_t* wb = hhbf + z * 4096;
  const float* bias = z ? bk : bq;
  bf16_t* out = z ? outk : outq;
  const float scale = z ? 1.0f : 0.08838834764831845f;

  const int blk = blockIdx.x;
  const int n = blk % NCH;
  const int h = (blk / NCH) % H_;
  const int b = blk / (NCH * H_);
  const int tid = threadIdx.x;
  const int lane = tid & 63;
  const int wv = tid >> 6;
  const int l15 = lane & 15;
  const int lhi = lane >> 4;

  if (z) {  // stage v^T early (global loads in flight under feats MFMA)
#pragma unroll
    for (int g = 0; g < 2; ++g) {
      int i8 = g * 256 + tid;
      int m = i8 >> 3, d8 = (i8 & 7) * 8;
      bf16x8 v8 = *(const bf16x8*)(pv + (size_t)(b * T_ + n * 64 + m) * D_ +
                                   h * 64 + d8);
#pragma unroll
      for (int jj = 0; jj < 8; ++jj) {
        int d = d8 + jj;
        vt[d * 64 + (m ^ ((d & 7) << 3))] = v8[jj];
      }
    }
  }

  // feats: y[t,e] = sum_d p[t,d] W[e,d]
  const int trowA = n * 64 + wv * 16 + l15;
  bf16x8 pa[2];
#pragma unroll
  for (int s = 0; s < 2; ++s)
    pa[s] = *(const bf16x8*)(p + (size_t)(b * T_ + trowA) * D_ + h * 64 +
                             s * 32 + lhi * 8);
  f32x4 acc[4] = {};
#pragma unroll
  for (int j = 0; j < 4; ++j)
#pragma unroll
    for (int s = 0; s < 2; ++s) {
      bf16x8 wf = *(const bf16x8*)(wb + (16 * j + l15) * 64 + s * 32 + lhi * 8);
      acc[j] = __builtin_amdgcn_mfma_f32_16x16x32_bf16(pa[s], wf, acc[j], 0, 0, 0);
    }
  float be[4];
#pragma unroll
  for (int j = 0; j < 4; ++j) be[j] = bias[16 * j + l15];

  // softmax over concat(y,-y); scatter bf16 feats to featT (swizzled)
#pragma unroll
  for (int r = 0; r < 4; ++r) {
    float y[4];
#pragma unroll
    for (int j = 0; j < 4; ++j) y[j] = acc[j][r] + be[j];
    float m = fmaxf(fmaxf(fabsf(y[0]), fabsf(y[1])),
                    fmaxf(fabsf(y[2]), fabsf(y[3])));
#pragma unroll
    for (int o = 1; o < 16; o <<= 1) m = fmaxf(m, __shfl_xor(m, o));
    float e1[4], e2[4], s = 0.f;
#pragma unroll
    for (int j = 0; j < 4; ++j) {
      e1[j] = __expf(y[j] - m);
      e2[j] = __expf(-y[j] - m);
      s += e1[j] + e2[j];
    }
#pragma unroll
    for (int o = 1; o < 16; o <<= 1) s += __shfl_xor(s, o);
    const float inv = scale / s;
    const int c = wv * 16 + lhi * 4 + r;
#pragma unroll
    for (int j = 0; j < 4; ++j) {
      const int f1 = 16 * j + l15, f2 = f1 + 64;
      featT[f1 * 64 + (((c >> 3) ^ swF(f1)) << 3) + (c & 7)] = (__bf16)(e1[j] * inv);
      featT[f2 * 64 + (((c >> 3) ^ swF(f2)) << 3) + (c & 7)] = (__bf16)(e2[j] * inv);
    }
  }
  __syncthreads();

  // coalesced global write [B,H,T,F] via column gather from featT
  const size_t obase = (size_t)(b * H_ + h) * T_ + n * 64;
#pragma unroll
  for (int g = 0; g < 4; ++g) {
    int i8 = g * 256 + tid;
    int t = i8 >> 4, fc = i8 & 15;
    bf16x8 o8;
#pragma unroll
    for (int jj = 0; jj < 8; ++jj) {
      int f = fc * 8 + jj;
      o8[jj] = featT[f * 64 + (((t >> 3) ^ swF(f)) << 3) + (t & 7)];
    }
    *(bf16x8*)(out + (obase + t) * F_ + fc * 8) = o8;
  }

  if (z) {  // kvT[d][f] via MFMA: A = vt rows d (c-contig), B = featT rows f
    const int drow = wv * 16 + l15;
    f32x4 a2[8] = {};
#pragma unroll
    for (int s = 0; s < 2; ++s) {
      const int c0 = s * 32 + lhi * 8;
      bf16x8 va = *(const bf16x8*)(vt + drow * 64 + (c0 ^ ((drow & 7) << 3)));
#pragma unroll
      for (int j = 0; j < 8; ++j) {
        const int fr = j * 16 + l15;
        bf16x8 kb = *(const bf16x8*)(featT + fr * 64 +
                                     ((((c0 >> 3) ^ swF(fr))) << 3));
        a2[j] = __builtin_amdgcn_mfma_f32_16x16x32_bf16(va, kb, a2[j], 0, 0, 0);
      }
    }
    bf16_t* ob = kvout + (size_t)blk * 8192;
#pragma unroll
    for (int j = 0; j < 8; ++j)
#pragma unroll
      for (int r = 0; r < 4; ++r) {
        int d = wv * 16 + lhi * 4 + r, f = j * 16 + l15;
        ob[d * 128 + f] = (__bf16)a2[j][r];
      }
  }
}

// ---------------------------------------------------------------------------
// K5: exclusive prefix over chunk axis, register-resident, bf16x8/thread
// ---------------------------------------------------------------------------
__global__ __launch_bounds__(256) void k_cumsum_excl(bf16_t* __restrict__ kv) {
  const int bh = blockIdx.x >> 2;
  const int slice = blockIdx.x & 3;
  const int e = slice * 2048 + threadIdx.x * 8;
  bf16_t* base = kv + (size_t)bh * NCH * 8192 + e;
  bf16x8 vals[NCH];
#pragma unroll
  for (int n = 0; n < NCH; ++n) vals[n] = *(const bf16x8*)(base + (size_t)n * 8192);
  float run[8] = {};
#pragma unroll
  for (int n = 0; n < NCH; ++n) {
    bf16x8 o;
#pragma unroll
    for (int j = 0; j < 8; ++j) {
      o[j] = (__bf16)run[j];
      run[j] += (float)vals[n][j];
    }
    *(bf16x8*)(base + (size_t)n * 8192) = o;
  }
}

// ---------------------------------------------------------------------------
// K6: o = q @ S_excl + tril(q k^T) @ v. k-tile and S^T-tile staged once via
// GLD16 (pre-swizzled source, chunk ^= row&7 within 16-chunk rows); q frags
// direct (wave-private). One barrier.
// ---------------------------------------------------------------------------
__global__ __launch_bounds__(256) void k_attn_chunk(
    const bf16_t* __restrict__ qf,   // [B,H,T,F]
    const bf16_t* __restrict__ kf,   // [B,H,T,F]
    const bf16_t* __restrict__ pv,   // [BT,D]
    const bf16_t* __restrict__ kvx,  // S_excl^T [B,H,N,HD,F]
    bf16_t* __restrict__ o_tmp) {    // [BT,D] (B,T,H,HD)
  __shared__ bf16_t kt[64 * 128];    // 16KB [t][f] swz
  __shared__ bf16_t st[64 * 128];    // 16KB [d][f] swz
  __shared__ bf16_t vt[64 * 64];     // 8KB
  __shared__ bf16_t scs[64 * 64];    // 8KB
  const int blk = blockIdx.x;
  const int n = blk % NCH;
  const int h = (blk / NCH) % H_;
  const int b = blk / (NCH * H_);
  const int tid = threadIdx.x;
  const int lane = tid & 63;
  const int wv = tid >> 6;
  const int l15 = lane & 15;
  const int lhi = lane >> 4;
  const size_t rowbase = (size_t)(b * H_ + h) * T_ + n * 64;
  const bf16_t* qb = qf + rowbase * F_;
  const bf16_t* kb = kf + rowbase * F_;
  const bf16_t* kvb = kvx + (size_t)blk * 8192;

  // GLD16 staging of kt/st: chunk_lin = g*256+tid; row=cl>>4, pc=cl&15;
  // content chunk cc = pc ^ (row&7) -> pre-swizzled source address
#pragma unroll
  for (int g = 0; g < 4; ++g) {
    const int cl = g * 256 + tid;
    const int row = cl >> 4, pc = cl & 15;
    const int cc = pc ^ (row & 7);
    const int lb = (g * 256 + wv * 64) * 8;   // elem base (wave-uniform)
    GLD16(kb + (size_t)row * F_ + cc * 8, kt + lb);
    GLD16(kvb + (size_t)row * F_ + cc * 8, st + lb);
  }
  // v^T staging (scalar swizzled writes)
#pragma unroll
  for (int g = 0; g < 2; ++g) {
    int i8 = g * 256 + tid;
    int m = i8 >> 3, d8 = (i8 & 7) * 8;
    bf16x8 v8 = *(const bf16x8*)(pv + (size_t)(b * T_ + n * 64 + m) * D_ +
                                 h * 64 + d8);
#pragma unroll
    for (int jj = 0; jj < 8; ++jj) {
      int d = d8 + jj;
      vt[d * 64 + (m ^ ((d & 7) << 3))] = v8[jj];
    }
  }
  // q A-frags (wave-private rows)
  bf16x8 qa[4];
#pragma unroll
  for (int s = 0; s < 4; ++s)
    qa[s] = *(const bf16x8*)(qb + (wv * 16 + l15) * F_ + s * 32 + lhi * 8);

  __syncthreads();   // drains GLD16 vmcnt + vt writes

  // scores = q @ k^T  (B-frags from kt LDS, swizzled)
  f32x4 accS[4] = {};
#pragma unroll
  for (int j = 0; j < 4; ++j) {
    const int tr = j * 16 + l15;
#pragma unroll
    for (int s = 0; s < 4; ++s) {
      bf16x8 kk = *(const bf16x8*)(kt + tr * 128 +
                                   (((s * 4 + lhi) ^ (tr & 7)) << 3));
      accS[j] = __builtin_amdgcn_mfma_f32_16x16x32_bf16(qa[s], kk, accS[j], 0, 0, 0);
    }
  }
#pragma unroll
  for (int j = 0; j < 4; ++j)
#pragma unroll
    for (int r = 0; r < 4; ++r) {
      int c = wv * 16 + lhi * 4 + r;
      int m = j * 16 + l15;
      float v = (m <= c) ? accS[j][r] : 0.f;
      scs[c * 64 + (m ^ ((c & 7) << 3))] = (__bf16)v;
    }

  // inter = q @ S_excl (B-frags from st LDS, swizzled)
  f32x4 acc[4] = {};
#pragma unroll
  for (int j = 0; j < 4; ++j) {
    const int dr = j * 16 + l15;
#pragma unroll
    for (int s = 0; s < 4; ++s) {
      bf16x8 sv = *(const bf16x8*)(st + dr * 128 +
                                   (((s * 4 + lhi) ^ (dr & 7)) << 3));
      acc[j] = __builtin_amdgcn_mfma_f32_16x16x32_bf16(qa[s], sv, acc[j], 0, 0, 0);
    }
  }

  // intra = sc @ v (scs same-wave rows; vt staged pre-barrier)
  const int crow = wv * 16 + l15;
#pragma unroll
  for (int s2 = 0; s2 < 2; ++s2) {
    const int m0 = s2 * 32 + lhi * 8;
    bf16x8 sa = *(const bf16x8*)(scs + crow * 64 + (m0 ^ ((crow & 7) << 3)));
#pragma unroll
    for (int j = 0; j < 4; ++j) {
      const int dr = j * 16 + l15;
      bf16x8 vb = *(const bf16x8*)(vt + dr * 64 + (m0 ^ ((dr & 7) << 3)));
      acc[j] = __builtin_amdgcn_mfma_f32_16x16x32_bf16(sa, vb, acc[j], 0, 0, 0);
    }
  }

#pragma unroll
  for (int j = 0; j < 4; ++j)
#pragma unroll
    for (int r = 0; r < 4; ++r) {
      int c = wv * 16 + lhi * 4 + r, d = j * 16 + l15;
      o_tmp[(size_t)(b * T_ + n * 64 + c) * D_ + h * 64 + d] = (__bf16)acc[j][r];
    }
}

// ---------------------------------------------------------------------------
// Workspace (bytes): total 168 MiB + 16 KiB
//   [0,16M)    x bf16 [BT,D] -> reused as o_tmp
//   [16M,22M)  wqkvT bf16 [3][N][K]
//   [22M,24M)  woT bf16 [N][K]
//   [24M,56M)  qf bf16 [B,H,T,F]
//   [56M,88M)  kf bf16 [B,H,T,F]
//   [88M,136M) pq,pk,pvb bf16 [3][BT,D]
//   [136M,168M) kvT bf16 [B,H,N,HD,F]   (no overlay: fused kernel reads pq/pk)
//   [168M,+16K) hh weights bf16 [2][64][64]
// ---------------------------------------------------------------------------
extern "C" void kernel_launch(void* const* d_in, const int* in_sizes, int n_in,
                              void* d_out, int out_size, void* d_ws, size_t ws_size,
                              hipStream_t stream) {
  const float* hs   = (const float*)d_in[0];
  const float* res  = (const float*)d_in[1];
  const float* nw   = (const float*)d_in[2];
  const float* w_q  = (const float*)d_in[3];
  const float* w_k  = (const float*)d_in[4];
  const float* w_v  = (const float*)d_in[5];
  const float* w_o  = (const float*)d_in[6];
  const float* hhqw = (const float*)d_in[7];
  const float* hhqb = (const float*)d_in[8];
  const float* hhkw = (const float*)d_in[9];
  const float* hhkb = (const float*)d_in[10];

  float* out       = (float*)d_out;
  float* o_final   = out;
  float* resid_out = out + BTD_;

  char* wsb = (char*)d_ws;
  bf16_t* x_bf  = (bf16_t*)(wsb);
  bf16_t* wqkvT = (bf16_t*)(wsb + (16ull << 20));
  bf16_t* woT   = (bf16_t*)(wsb + (22ull << 20));
  bf16_t* qf    = (bf16_t*)(wsb + (24ull << 20));
  bf16_t* kf    = (bf16_t*)(wsb + (56ull << 20));
  bf16_t* pqkv  = (bf16_t*)(wsb + (88ull << 20));
  bf16_t* pq    = pqkv;
  bf16_t* pk    = pqkv + (size_t)BTD_;
  bf16_t* pvb   = pqkv + (size_t)2 * BTD_;
  bf16_t* kv    = (bf16_t*)(wsb + (136ull << 20));
  bf16_t* hhbf  = (bf16_t*)(wsb + (168ull << 20));
  bf16_t* o_tmp = x_bf;

  k_transpose_all<<<dim3(16, 16, 5), 256, 0, stream>>>(
      w_q, w_k, w_v, w_o, hhqw, hhkw, wqkvT, woT, hhbf);

  k_add_rmsnorm<<<BT_, 256, 0, stream>>>(hs, res, nw, resid_out, x_bf);

  k_gemm_mfma<0><<<dim3(8, 64, 3), 256, 0, stream>>>(x_bf, wqkvT, (void*)pqkv);

  k_hedgehog_kv<<<dim3(2048, 2), 256, 0, stream>>>(pq, pk, hhbf, hhqb, hhkb,
                                                   pvb, qf, kf, kv);

  k_cumsum_excl<<<256, 256, 0, stream>>>(kv);

  k_attn_chunk<<<2048, 256, 0, stream>>>(qf, kf, pvb, kv, o_tmp);

  k_gemm_mfma<1><<<dim3(8, 64, 1), 256, 0, stream>>>(o_tmp, woT, (void*)o_final);
}